// Round 4
// baseline (378.778 us; speedup 1.0000x reference)
//
#include <hip/hip_runtime.h>

// Depthwise 7x7 true-convolution (flipped kernel, SAME zero pad) + mish.
// x: [16,64,256,256] f32, kernel: [7,7] f32 (shared by all planes).
//
// Pure streaming, no LDS, no barriers. Thread = (plane, 8-col strip, 32-row
// block). Slides down 38 input rows; ring of 8 accumulator rows (static
// indices -> registers). Per input row ir: 4 aligned float4 loads (window
// cols 8s-4..8s+11), 7x7x8 = 392 FMAs scattered into the 7 live output rows
// (p = ir - or + 3), then output row ir-3 completes: mish + 2 float4 stores.
// Horizontal halo overlap between lanes is L1-served; vertical halo within
// thread is register-served. Grid = 4 blocks/CU exactly, all-resident.

#define HW 256

__device__ __forceinline__ float mish_f(float y) {
    float t = __expf(y);            // inf-safe: d -> inf -> 2/d -> 0 -> y*1
    float u = 1.0f + t;
    float d = __fmaf_rn(u, u, 1.0f);
    return y * (1.0f - __fdividef(2.0f, d));
}

__global__ __launch_bounds__(256, 4)
void dwconv7_mish_stream(const float* __restrict__ x,
                         const float* __restrict__ kern,
                         float* __restrict__ out) {
    const int tid   = threadIdx.x;
    const int strip = tid & 31;          // 32 strips x 8 cols = 256 wide
    const int psub  = tid >> 5;          // 8 planes per block
    const int rb    = blockIdx.x;        // 8 row-blocks of 32 rows
    const int pg    = blockIdx.y;        // 128 plane-groups
    const int plane = (pg << 3) + psub;  // 0..1023
    const int r0    = rb << 5;

    // Flipped kernel into SGPRs: kf[p*7+q] = kern[6-p][6-q]
    float kf[49];
    #pragma unroll
    for (int i = 0; i < 49; ++i) {
        int p = i / 7, q = i - p * 7;
        kf[i] = __int_as_float(__builtin_amdgcn_readfirstlane(
                    __float_as_int(kern[(6 - p) * 7 + (6 - q)])));
    }

    // Column granule element-bases (row 0), clamped to the plane row.
    // Granule k covers window floats v[4k..4k+3] = cols 8*strip-4+4k ..+3.
    int e[4];
    #pragma unroll
    for (int k = 0; k < 4; ++k) {
        int g = 2 * strip - 1 + k;
        g = g < 0 ? 0 : (g > 63 ? 63 : g);
        e[k] = (plane << 16) + (g << 2);
    }
    // Zero-pad masks: strip 0 needs v[1..3]=0, strip 31 needs v[12..14]=0
    // (v[0], v[15] are never used).
    const unsigned mlo = (strip == 0)  ? 0u : 0xffffffffu;
    const unsigned mhi = (strip == 31) ? 0u : 0xffffffffu;

    float acc[8][8];
    #pragma unroll
    for (int a = 0; a < 8; ++a)
        #pragma unroll
        for (int c = 0; c < 8; ++c) acc[a][c] = 0.f;

    const int obase = (plane << 16) + (strip << 3);

    // it = 0..39 ; input row ir = r0 + it - 3 ; output row it-6 completes.
    // Ring slot arithmetic static because it0 is a multiple of 8.
    #pragma unroll 1
    for (int it0 = 0; it0 < 40; it0 += 8) {
        #pragma unroll
        for (int s = 0; s < 8; ++s) {
            const int it = it0 + s;
            const int gr = r0 + it - 3;
            float4 a0, a1, a2, a3;
            if ((unsigned)gr < (unsigned)HW && it < 38) {  // uniform branch
                const int ro = gr << 8;
                a0 = *(const float4*)(x + e[0] + ro);
                a1 = *(const float4*)(x + e[1] + ro);
                a2 = *(const float4*)(x + e[2] + ro);
                a3 = *(const float4*)(x + e[3] + ro);
            } else {
                a0 = a1 = a2 = a3 = make_float4(0.f, 0.f, 0.f, 0.f);
            }
            float v[16] = {a0.x, a0.y, a0.z, a0.w,  a1.x, a1.y, a1.z, a1.w,
                           a2.x, a2.y, a2.z, a2.w,  a3.x, a3.y, a3.z, a3.w};
            v[1]  = __uint_as_float(__float_as_uint(v[1])  & mlo);
            v[2]  = __uint_as_float(__float_as_uint(v[2])  & mlo);
            v[3]  = __uint_as_float(__float_as_uint(v[3])  & mlo);
            v[12] = __uint_as_float(__float_as_uint(v[12]) & mhi);
            v[13] = __uint_as_float(__float_as_uint(v[13]) & mhi);
            v[14] = __uint_as_float(__float_as_uint(v[14]) & mhi);

            // Input row ir feeds output rows or = ir-3+d (d=0..6), kernel
            // row p = 6-d; ring slot(or) = (s+2+d)&7. Out-of-range "or"
            // accumulate garbage into slots that are never stored.
            #pragma unroll
            for (int d = 0; d < 7; ++d) {
                const int slot = (s + 2 + d) & 7;
                const int p = 6 - d;
                #pragma unroll
                for (int q = 0; q < 7; ++q) {
                    const float w = kf[p * 7 + q];
                    #pragma unroll
                    for (int c = 0; c < 8; ++c)
                        acc[slot][c] = fmaf(v[c + q + 1], w, acc[slot][c]);
                }
            }

            // Output row od = it-6 is complete (slot (s+2)&7).
            const int od = it - 6;
            const int fs = (s + 2) & 7;
            if ((unsigned)od < 32u) {                      // uniform branch
                float4 o0, o1;
                o0.x = mish_f(acc[fs][0]); o0.y = mish_f(acc[fs][1]);
                o0.z = mish_f(acc[fs][2]); o0.w = mish_f(acc[fs][3]);
                o1.x = mish_f(acc[fs][4]); o1.y = mish_f(acc[fs][5]);
                o1.z = mish_f(acc[fs][6]); o1.w = mish_f(acc[fs][7]);
                float* dst = out + obase + ((r0 + od) << 8);
                *(float4*)(dst)     = o0;
                *(float4*)(dst + 4) = o1;
            }
            #pragma unroll
            for (int c = 0; c < 8; ++c) acc[fs][c] = 0.f;  // recycle slot
        }
    }
}

extern "C" void kernel_launch(void* const* d_in, const int* in_sizes, int n_in,
                              void* d_out, int out_size, void* d_ws, size_t ws_size,
                              hipStream_t stream) {
    const float* x = (const float*)d_in[0];
    const float* k = (const float*)d_in[1];
    float* out = (float*)d_out;

    dim3 grid(8, 128, 1);    // 1024 blocks = exactly 4 blocks/CU resident
    dim3 block(256);
    dwconv7_mish_stream<<<grid, block, 0, stream>>>(x, k, out);
}